// Round 1
// baseline (116.388 us; speedup 1.0000x reference)
//
#include <hip/hip_runtime.h>

typedef unsigned int  u32;
typedef unsigned short u16;

typedef float f4  __attribute__((ext_vector_type(4)));
typedef short bf8 __attribute__((ext_vector_type(8)));

#define NBLK  512
#define ITERS 8   // 512 blocks * 8 iters * 64 boards = 262144

// round-to-nearest-even fp32 -> bf16 bits
__device__ __forceinline__ u32 bfr(float f) {
    union { float f; u32 u; } v; v.f = f;
    return (v.u + 0x7fffu + ((v.u >> 16) & 1u)) >> 16;
}
__device__ __forceinline__ u32 pk2(float lo, float hi) {
    return bfr(lo) | (bfr(hi) << 16);
}
__device__ __forceinline__ float blo(u32 u) { union { u32 u; float f; } v; v.u = u << 16;        return v.f; }
__device__ __forceinline__ float bhi(u32 u) { union { u32 u; float f; } v; v.u = u & 0xffff0000u; return v.f; }
// reverse 4 nibbles of a 16-bit row
__device__ __forceinline__ u32 nrev(u32 x) {
    return ((x >> 12) & 0xFu) | ((x >> 4) & 0xF0u) | ((x << 4) & 0xF00u) | ((x << 12) & 0xF000u);
}

__launch_bounds__(256, 2)
__global__ void smartcnn_fused(const int* __restrict__ exps,
                               const float* __restrict__ c0w, const float* __restrict__ c0b,
                               const float* __restrict__ c1w,
                               const float* __restrict__ lw,  const float* __restrict__ lb,
                               const float* __restrict__ ow,  const float* __restrict__ ob,
                               float* __restrict__ out)
{
    __shared__ float4 P01[44];          // [c][v]: (TA0,TB0,TA1,TB1), bias/mask folded in
    __shared__ u16    z1[4 * 16 * 96];  // [G][m][k] bf16
    __shared__ float4 Pbuf[4][4][16];   // [G][wave][m] logit partials
    __shared__ u32    flg[64];          // [G*16+m] flip flags

    const int tid  = threadIdx.x;
    const int w    = tid >> 6;    // wave 0..3: owns feature rows 64w..64w+63
    const int lane = tid & 63;
    const int m    = lane & 15;
    const int qd   = lane >> 4;   // quad 0..3 (= conv channel in phase 1)

    // ---- stage pair tables (conv folded to lookups) ----
    if (tid < 44) {
        int c = tid / 11, v = tid % 11;
        float ta0 = c0w[c*24 + 0] + c0w[c*24 + (1+v)*2 + 0] + c0b[c];
        float tb0 = c0w[c*24 + 1] + c0w[c*24 + (1+v)*2 + 1];
        float ta1 = c1w[c*24 + 0] + c1w[c*24 + (1+v)*2 + 0];
        float tb1 = c1w[c*24 + 1] + c1w[c*24 + (1+v)*2 + 1];
        P01[tid] = make_float4(ta0, tb0, ta1, tb1);
    }

    // ---- preload W A-fragments (rows 64w..64w+63, K=96) into registers ----
    bf8 af[4][3];
    #pragma unroll
    for (int tt = 0; tt < 4; ++tt) {
        #pragma unroll
        for (int s = 0; s < 3; ++s) {
            const float* src = lw + ((size_t)((w*4 + tt)*16 + m))*96 + s*32 + qd*8;
            float4 x0 = *(const float4*)(src);
            float4 x1 = *(const float4*)(src + 4);
            union { u32 u[4]; bf8 v; } cv;
            cv.u[0] = pk2(x0.x, x0.y); cv.u[1] = pk2(x0.z, x0.w);
            cv.u[2] = pk2(x1.x, x1.y); cv.u[3] = pk2(x1.z, x1.w);
            af[tt][s] = cv.v;
        }
    }
    // ---- preload out_w (bf16 pairs) + linear_b for this lane's feature rows ----
    u32 owp[4][4][2]; float lbr[4][4];
    #pragma unroll
    for (int tt = 0; tt < 4; ++tt) {
        #pragma unroll
        for (int r = 0; r < 4; ++r) {
            int n = (w*4 + tt)*16 + qd*4 + r;
            owp[tt][r][0] = pk2(ow[0*256 + n], ow[1*256 + n]);
            owp[tt][r][1] = pk2(ow[2*256 + n], ow[3*256 + n]);
            lbr[tt][r] = lb[n];
        }
    }
    const float4 obv = *(const float4*)ob;

    __syncthreads();

    const int boardBase0 = blockIdx.x * (ITERS * 64);
    // prefetch first iteration's exponents: lane (qd,m) loads row qd of board m (group w)
    int4 e4 = *(const int4*)(exps + (size_t)(boardBase0 + w*16 + m)*16 + qd*4);

    for (int it = 0; it < ITERS; ++it) {
        const int base = boardBase0 + it*64;

        // ================= phase 1: build z1 for group G = w =================
        u32 p = (u32)e4.x | ((u32)e4.y << 4) | ((u32)e4.z << 8) | ((u32)e4.w << 12);
        u32 R0 = (u32)__shfl((int)p, m);
        u32 R1 = (u32)__shfl((int)p, m + 16);
        u32 R2 = (u32)__shfl((int)p, m + 32);
        u32 R3 = (u32)__shfl((int)p, m + 48);
        // corners of UNFLIPPED board; argmax first-max-wins
        u32 c0v = R0 & 15u, c1v = (R0 >> 12) & 15u, c2v = R3 & 15u, c3v = (R3 >> 12) & 15u;
        u32 best = c0v; int ix = 0;
        if (c1v > best) { best = c1v; ix = 1; }
        if (c2v > best) { best = c2v; ix = 2; }
        if (c3v > best) { best = c3v; ix = 3; }
        const bool fv = (ix >= 2), fh = ((ix & 1) != 0);
        u32 F0 = fv ? R3 : R0;
        u32 F1 = fv ? R2 : R1;
        u32 F2 = fv ? R1 : R2;
        u32 F3 = fv ? R0 : R3;
        F0 = fh ? nrev(F0) : F0;
        F1 = fh ? nrev(F1) : F1;
        F2 = fh ? nrev(F2) : F2;
        F3 = fh ? nrev(F3) : F3;

        if (qd == 0) flg[w*16 + m] = (u32)fv | ((u32)fh << 1);

        const float4* Tc = &P01[qd * 11];  // this lane's channel tables
        float4 q0_0 = Tc[F0 & 15u], q0_1 = Tc[(F0 >> 4) & 15u], q0_2 = Tc[(F0 >> 8) & 15u], q0_3 = Tc[(F0 >> 12) & 15u];
        float4 q1_0 = Tc[F1 & 15u], q1_1 = Tc[(F1 >> 4) & 15u], q1_2 = Tc[(F1 >> 8) & 15u], q1_3 = Tc[(F1 >> 12) & 15u];
        float4 q2_0 = Tc[F2 & 15u], q2_1 = Tc[(F2 >> 4) & 15u], q2_2 = Tc[(F2 >> 8) & 15u], q2_3 = Tc[(F2 >> 12) & 15u];
        float4 q3_0 = Tc[F3 & 15u], q3_1 = Tc[(F3 >> 4) & 15u], q3_2 = Tc[(F3 >> 8) & 15u], q3_3 = Tc[(F3 >> 12) & 15u];
        // zh[c,i,j] (j=0..2), zv[c,i,j] (i=0..2)
        float h0  = fmaxf(q0_0.x + q0_1.y, 0.f), h1  = fmaxf(q0_1.x + q0_2.y, 0.f), h2  = fmaxf(q0_2.x + q0_3.y, 0.f);
        float h3  = fmaxf(q1_0.x + q1_1.y, 0.f), h4  = fmaxf(q1_1.x + q1_2.y, 0.f), h5  = fmaxf(q1_2.x + q1_3.y, 0.f);
        float h6  = fmaxf(q2_0.x + q2_1.y, 0.f), h7  = fmaxf(q2_1.x + q2_2.y, 0.f), h8  = fmaxf(q2_2.x + q2_3.y, 0.f);
        float h9  = fmaxf(q3_0.x + q3_1.y, 0.f), h10 = fmaxf(q3_1.x + q3_2.y, 0.f), h11 = fmaxf(q3_2.x + q3_3.y, 0.f);
        float v0  = fmaxf(q0_0.z + q1_0.w, 0.f), v1  = fmaxf(q0_1.z + q1_1.w, 0.f);
        float v2  = fmaxf(q0_2.z + q1_2.w, 0.f), v3  = fmaxf(q0_3.z + q1_3.w, 0.f);
        float v4  = fmaxf(q1_0.z + q2_0.w, 0.f), v5  = fmaxf(q1_1.z + q2_1.w, 0.f);
        float v6  = fmaxf(q1_2.z + q2_2.w, 0.f), v7  = fmaxf(q1_3.z + q2_3.w, 0.f);
        float v8  = fmaxf(q2_0.z + q3_0.w, 0.f), v9  = fmaxf(q2_1.z + q3_1.w, 0.f);
        float v10 = fmaxf(q2_2.z + q3_2.w, 0.f), v11 = fmaxf(q2_3.z + q3_3.w, 0.f);

        u16* zrow = &z1[(w*16 + m)*96];
        { // zh run: features c*12 + (i*3+j), contiguous 12
            uint2* ph = (uint2*)(zrow + qd*12);
            ph[0] = make_uint2(pk2(h0, h1), pk2(h2, h3));
            ph[1] = make_uint2(pk2(h4, h5), pk2(h6, h7));
            ph[2] = make_uint2(pk2(h8, h9), pk2(h10, h11));
            // zv run: features 48 + c*12 + (i*4+j)
            uint2* pv = (uint2*)(zrow + 48 + qd*12);
            pv[0] = make_uint2(pk2(v0, v1), pk2(v2, v3));
            pv[1] = make_uint2(pk2(v4, v5), pk2(v6, v7));
            pv[2] = make_uint2(pk2(v8, v9), pk2(v10, v11));
        }

        // prefetch next iteration's exponents (hide HBM latency behind GEMM)
        if (it + 1 < ITERS)
            e4 = *(const int4*)(exps + (size_t)(boardBase0 + (it+1)*64 + w*16 + m)*16 + qd*4);

        __syncthreads();  // z1 ready (all groups)

        // ================= GEMM1 (MFMA) + GEMM2 (VALU, in-register) =================
        bf8 zb[4][3];
        #pragma unroll
        for (int G = 0; G < 4; ++G)
            #pragma unroll
            for (int s = 0; s < 3; ++s)
                zb[G][s] = *(const bf8*)(&z1[(G*16 + m)*96 + s*32 + qd*8]);

        float P[4][4] = {};  // [G][action] partial logits over this lane's features
        #pragma unroll
        for (int tt = 0; tt < 4; ++tt) {
            f4 acc[4] = {{0.f,0.f,0.f,0.f},{0.f,0.f,0.f,0.f},{0.f,0.f,0.f,0.f},{0.f,0.f,0.f,0.f}};
            #pragma unroll
            for (int s = 0; s < 3; ++s) {
                #pragma unroll
                for (int G = 0; G < 4; ++G)
                    acc[G] = __builtin_amdgcn_mfma_f32_16x16x32_bf16(af[tt][s], zb[G][s], acc[G], 0, 0, 0);
            }
            // lane holds D rows = features (w*4+tt)*16 + qd*4 + r, col = board m
            #pragma unroll
            for (int r = 0; r < 4; ++r) {
                float w0f = blo(owp[tt][r][0]), w1f = bhi(owp[tt][r][0]);
                float w2f = blo(owp[tt][r][1]), w3f = bhi(owp[tt][r][1]);
                float lbv = lbr[tt][r];
                #pragma unroll
                for (int G = 0; G < 4; ++G) {
                    float z = fmaxf(acc[G][r] + lbv, 0.f);   // relu(z2)
                    P[G][0] = fmaf(z, w0f, P[G][0]);
                    P[G][1] = fmaf(z, w1f, P[G][1]);
                    P[G][2] = fmaf(z, w2f, P[G][2]);
                    P[G][3] = fmaf(z, w3f, P[G][3]);
                }
            }
        }

        // reduce across quads (features within this wave), then stage for cross-wave sum
        #pragma unroll
        for (int G = 0; G < 4; ++G) {
            #pragma unroll
            for (int a = 0; a < 4; ++a) {
                P[G][a] += __shfl_xor(P[G][a], 16);
                P[G][a] += __shfl_xor(P[G][a], 32);
            }
        }
        if (qd == 0) {
            #pragma unroll
            for (int G = 0; G < 4; ++G)
                Pbuf[G][w][m] = make_float4(P[G][0], P[G][1], P[G][2], P[G][3]);
        }
        __syncthreads();

        // ================= epilogue: lane (qd,m) owns board base + qd*16 + m =================
        {
            float4 s0 = Pbuf[qd][0][m], s1 = Pbuf[qd][1][m], s2 = Pbuf[qd][2][m], s3 = Pbuf[qd][3][m];
            float L0 = s0.x + s1.x + s2.x + s3.x + obv.x;
            float L1 = s0.y + s1.y + s2.y + s3.y + obv.y;
            float L2 = s0.z + s1.z + s2.z + s3.z + obv.z;
            float L3 = s0.w + s1.w + s2.w + s3.w + obv.w;
            float mx = fmaxf(fmaxf(L0, L1), fmaxf(L2, L3));
            float e0 = __expf(L0 - mx), e1 = __expf(L1 - mx), e2 = __expf(L2 - mx), e3 = __expf(L3 - mx);
            float inv = 1.0f / (e0 + e1 + e2 + e3);
            float p0 = e0 * inv, p1 = e1 * inv, p2 = e2 * inv, p3 = e3 * inv;
            u32 fl = flg[qd*16 + m];
            float4 o;
            o.x = (fl & 1u) ? p1 : p0;   // actions 0,1 swap on flip_v
            o.y = (fl & 1u) ? p0 : p1;
            o.z = (fl & 2u) ? p3 : p2;   // actions 2,3 swap on flip_h
            o.w = (fl & 2u) ? p2 : p3;
            *(float4*)(out + (size_t)(base + qd*16 + m) * 4) = o;
        }
        __syncthreads();  // protect z1/flg/Pbuf before next iteration overwrites
    }
}

extern "C" void kernel_launch(void* const* d_in, const int* in_sizes, int n_in,
                              void* d_out, int out_size, void* d_ws, size_t ws_size,
                              hipStream_t stream) {
    const int*   exps = (const int*)  d_in[0];
    const float* c0w  = (const float*)d_in[1];
    const float* c0b  = (const float*)d_in[2];
    const float* c1w  = (const float*)d_in[3];
    const float* lw   = (const float*)d_in[4];
    const float* lbv  = (const float*)d_in[5];
    const float* oww  = (const float*)d_in[6];
    const float* obv  = (const float*)d_in[7];
    smartcnn_fused<<<NBLK, 256, 0, stream>>>(exps, c0w, c0b, c1w, lw, lbv, oww, obv, (float*)d_out);
}